// Round 1
// baseline (1591.851 us; speedup 1.0000x reference)
//
#include <hip/hip_runtime.h>

// EMD approx-match (Fan et al. approxmatch.cu), B=8, N=M=4096.
// 10 annealing levels x 3 sweeps over the implicit [N,M] distance matrix.
// d2 recomputed on the fly from LDS-staged points -> compute-bound.

#define BB 8
#define NN 4096
#define MM 4096

constexpr int ROWS = 32;   // rows (or cols) owned per block
constexpr int S    = 8;    // strided split of the inner loop across threads
constexpr int BLK  = 256;  // ROWS * S

#if defined(__has_builtin)
#if __has_builtin(__builtin_amdgcn_exp2f)
#define EXP2F(x) __builtin_amdgcn_exp2f(x)
#endif
#endif
#ifndef EXP2F
#define EXP2F(x) exp2f(x)
#endif

__global__ void emd_init(float* __restrict__ satl, float* __restrict__ satr,
                         float* __restrict__ out) {
    int i = blockIdx.x * blockDim.x + threadIdx.x;
    if (i < BB * NN) satl[i] = 1.0f;   // factorl = max(N,M)/N = 1
    if (i < BB * MM) satr[i] = 1.0f;   // factorr = 1
    if (i == 0) out[0] = 0.0f;
}

// Pass A: rowsum over m, write sl[n] = satl[n] / (sum_m e*satr[m] + 1e-9)
__global__ __launch_bounds__(BLK) void emd_passA(
        const float* __restrict__ xyz1, const float* __restrict__ xyz2,
        const float* __restrict__ satl, const float* __restrict__ satr,
        float* __restrict__ sl, float c) {
    __shared__ float4 q[MM];                     // (x2,y2,z2,satr[m]) 64 KB
    const int b    = blockIdx.x / (NN / ROWS);
    const int tile = blockIdx.x % (NN / ROWS);
    const float* x2b = xyz2 + (size_t)b * MM * 3;
    const float* srb = satr + (size_t)b * MM;
    for (int m = threadIdx.x; m < MM; m += BLK)
        q[m] = make_float4(x2b[3*m], x2b[3*m+1], x2b[3*m+2], srb[m]);
    __syncthreads();

    const int r = threadIdx.x >> 3, s = threadIdx.x & 7;
    const int n = tile * ROWS + r;
    const float* p = xyz1 + ((size_t)b * NN + n) * 3;
    const float x1 = p[0], y1 = p[1], z1 = p[2];

    float acc = 0.0f;
    #pragma unroll 4
    for (int j = 0; j < MM / S; ++j) {
        float4 v = q[j * S + s];
        float dx = x1 - v.x, dy = y1 - v.y, dz = z1 - v.z;
        float d2 = fmaf(dx, dx, fmaf(dy, dy, dz * dz));
        float e  = EXP2F(c * d2);
        acc = fmaf(e, v.w, acc);
    }
    acc += __shfl_xor(acc, 1);
    acc += __shfl_xor(acc, 2);
    acc += __shfl_xor(acc, 4);
    if (s == 0) {
        int gi = b * NN + n;
        sl[gi] = satl[gi] / (acc + 1e-9f);
    }
}

// Pass B: colsum ss2[m] = satr[m] * sum_n e*sl[n]; fused ratio + satr update.
__global__ __launch_bounds__(BLK) void emd_passB(
        const float* __restrict__ xyz1, const float* __restrict__ xyz2,
        const float* __restrict__ sl, float* __restrict__ satr,
        float* __restrict__ sr2, float c) {
    __shared__ float4 p[NN];                     // (x1,y1,z1,sl[n]) 64 KB
    const int b    = blockIdx.x / (MM / ROWS);
    const int tile = blockIdx.x % (MM / ROWS);
    const float* x1b = xyz1 + (size_t)b * NN * 3;
    const float* slb = sl + (size_t)b * NN;
    for (int n = threadIdx.x; n < NN; n += BLK)
        p[n] = make_float4(x1b[3*n], x1b[3*n+1], x1b[3*n+2], slb[n]);
    __syncthreads();

    const int r = threadIdx.x >> 3, s = threadIdx.x & 7;
    const int m = tile * ROWS + r;
    const float* qp = xyz2 + ((size_t)b * MM + m) * 3;
    const float x2 = qp[0], y2 = qp[1], z2 = qp[2];
    const int gi = b * MM + m;
    const float sr = satr[gi];

    float acc = 0.0f;
    #pragma unroll 4
    for (int j = 0; j < NN / S; ++j) {
        float4 v = p[j * S + s];
        float dx = v.x - x2, dy = v.y - y2, dz = v.z - z2;
        float d2 = fmaf(dx, dx, fmaf(dy, dy, dz * dz));
        float e  = EXP2F(c * d2);
        acc = fmaf(e, v.w, acc);
    }
    acc += __shfl_xor(acc, 1);
    acc += __shfl_xor(acc, 2);
    acc += __shfl_xor(acc, 4);
    if (s == 0) {
        float ss2   = acc * sr;
        float ratio = fminf(sr / (ss2 + 1e-9f), 1.0f);
        sr2[gi]  = sr * ratio;                       // satr_old * ratio (for pass C)
        satr[gi] = fmaxf(sr - ss2 * ratio, 0.0f);    // next level's satr
    }
}

// Pass C: cost += w*ratio*d2, fused satl update. w*ratio = e*sr2[m]*sl[n].
__global__ __launch_bounds__(BLK) void emd_passC(
        const float* __restrict__ xyz1, const float* __restrict__ xyz2,
        const float* __restrict__ sl, float* __restrict__ satl,
        const float* __restrict__ sr2, float* __restrict__ out, float c) {
    __shared__ float4 q[MM];                     // (x2,y2,z2,sr2[m]) 64 KB
    const int b    = blockIdx.x / (NN / ROWS);
    const int tile = blockIdx.x % (NN / ROWS);
    const float* x2b = xyz2 + (size_t)b * MM * 3;
    const float* s2b = sr2 + (size_t)b * MM;
    for (int m = threadIdx.x; m < MM; m += BLK)
        q[m] = make_float4(x2b[3*m], x2b[3*m+1], x2b[3*m+2], s2b[m]);
    __syncthreads();

    const int r = threadIdx.x >> 3, s = threadIdx.x & 7;
    const int n = tile * ROWS + r;
    const float* pp = xyz1 + ((size_t)b * NN + n) * 3;
    const float x1 = pp[0], y1 = pp[1], z1 = pp[2];
    const int gi = b * NN + n;
    const float sln = sl[gi];

    float rd = 0.0f, cost = 0.0f;
    #pragma unroll 4
    for (int j = 0; j < MM / S; ++j) {
        float4 v = q[j * S + s];
        float dx = x1 - v.x, dy = y1 - v.y, dz = z1 - v.z;
        float d2 = fmaf(dx, dx, fmaf(dy, dy, dz * dz));
        float e  = EXP2F(c * d2);
        float t  = e * v.w;          // e * satr_old[m] * ratio[m]
        rd += t;
        cost = fmaf(t, d2, cost);
    }
    // satl decrement: reduce rd over the 8-way split only
    rd += __shfl_xor(rd, 1);
    rd += __shfl_xor(rd, 2);
    rd += __shfl_xor(rd, 4);
    if (s == 0) satl[gi] = fmaxf(satl[gi] - rd * sln, 0.0f);

    // cost: scale by this row's sl, then full-wave reduce, one atomic per wave
    cost *= sln;
    cost += __shfl_xor(cost, 1);
    cost += __shfl_xor(cost, 2);
    cost += __shfl_xor(cost, 4);
    cost += __shfl_xor(cost, 8);
    cost += __shfl_xor(cost, 16);
    cost += __shfl_xor(cost, 32);
    if ((threadIdx.x & 63) == 0)
        atomicAdd(out, cost * (1.0f / (float)(BB * NN)));
}

extern "C" void kernel_launch(void* const* d_in, const int* in_sizes, int n_in,
                              void* d_out, int out_size, void* d_ws, size_t ws_size,
                              hipStream_t stream) {
    const float* xyz1 = (const float*)d_in[0];   // [B,N,3]
    const float* xyz2 = (const float*)d_in[1];   // [B,M,3]
    float* out  = (float*)d_out;                 // scalar

    float* satl = (float*)d_ws;                  // B*N
    float* sl   = satl + BB * NN;                // B*N
    float* satr = sl   + BB * NN;                // B*M
    float* sr2  = satr + BB * MM;                // B*M   (total 512 KB)

    emd_init<<<(BB * NN + 255) / 256, 256, 0, stream>>>(satl, satr, out);

    const double levels[10] = {-16384.0, -4096.0, -1024.0, -256.0, -64.0,
                               -16.0, -4.0, -1.0, -0.25, 0.0};
    const double LOG2E = 1.4426950408889634;
    for (int l = 0; l < 10; ++l) {
        float c = (float)(levels[l] * LOG2E);    // exp(level*d2) = exp2(c*d2)
        emd_passA<<<BB * (NN / ROWS), BLK, 0, stream>>>(xyz1, xyz2, satl, satr, sl, c);
        emd_passB<<<BB * (MM / ROWS), BLK, 0, stream>>>(xyz1, xyz2, sl, satr, sr2, c);
        emd_passC<<<BB * (NN / ROWS), BLK, 0, stream>>>(xyz1, xyz2, sl, satl, sr2, out, c);
    }
}

// Round 2
// 1069.772 us; speedup vs baseline: 1.4880x; 1.4880x over previous
//
#include <hip/hip_runtime.h>

// EMD approx-match (Fan et al. approxmatch.cu), B=8, N=M=4096.
// Register-tiled (4 rows/thread per LDS read) + fused passC(l)+passA(l+1):
// 21 full [N,M] sweeps instead of 30, each VALU-bound instead of LDS-bound.

#define BB 8
#define NN 4096
#define MM 4096

constexpr int BLK   = 256;  // threads per block (4 waves)
constexpr int S     = 16;   // inner-loop (m or n) split lanes per row-group
constexpr int R     = 4;    // rows (or cols) per thread
constexpr int RPB   = (BLK / S) * R;   // 64 rows per block
constexpr int CHUNK = 2048; // CA kernel LDS chunk of the m dimension

#if defined(__has_builtin)
#if __has_builtin(__builtin_amdgcn_exp2f)
#define EXP2F(x) __builtin_amdgcn_exp2f(x)
#endif
#endif
#ifndef EXP2F
#define EXP2F(x) exp2f(x)
#endif

__global__ void emd_init(float* __restrict__ satl, float* __restrict__ satr,
                         float* __restrict__ out) {
    int i = blockIdx.x * blockDim.x + threadIdx.x;
    if (i < BB * NN) satl[i] = 1.0f;   // factorl = max(N,M)/N = 1
    if (i < BB * MM) satr[i] = 1.0f;   // factorr = 1
    if (i == 0) out[0] = 0.0f;
}

// Pass A (first level only): sl[n] = satl[n] / (sum_m e*satr[m] + 1e-9)
__global__ __launch_bounds__(BLK) void emd_passA(
        const float* __restrict__ xyz1, const float* __restrict__ xyz2,
        const float* __restrict__ satl, const float* __restrict__ satr,
        float* __restrict__ sl, float c) {
    __shared__ float4 q[MM];                     // (x2,y2,z2,satr[m]) 64 KB
    const int b    = blockIdx.x / (NN / RPB);
    const int tile = blockIdx.x % (NN / RPB);
    const float* x2b = xyz2 + (size_t)b * MM * 3;
    const float* srb = satr + (size_t)b * MM;
    for (int m = threadIdx.x; m < MM; m += BLK)
        q[m] = make_float4(x2b[3*m], x2b[3*m+1], x2b[3*m+2], srb[m]);
    __syncthreads();

    const int g = threadIdx.x / S, s = threadIdx.x % S;
    const int n0 = tile * RPB + g * R;
    const float* p = xyz1 + ((size_t)b * NN + n0) * 3;
    float x1[R], y1[R], z1[R], acc[R];
    #pragma unroll
    for (int r = 0; r < R; ++r) {
        x1[r] = p[3*r]; y1[r] = p[3*r+1]; z1[r] = p[3*r+2]; acc[r] = 0.0f;
    }

    #pragma unroll 2
    for (int j = 0; j < MM / S; ++j) {
        float4 v = q[j * S + s];
        #pragma unroll
        for (int r = 0; r < R; ++r) {
            float dx = x1[r]-v.x, dy = y1[r]-v.y, dz = z1[r]-v.z;
            float d2 = fmaf(dx, dx, fmaf(dy, dy, dz * dz));
            acc[r] = fmaf(EXP2F(c * d2), v.w, acc[r]);
        }
    }
    #pragma unroll
    for (int r = 0; r < R; ++r) {
        acc[r] += __shfl_xor(acc[r], 1);
        acc[r] += __shfl_xor(acc[r], 2);
        acc[r] += __shfl_xor(acc[r], 4);
        acc[r] += __shfl_xor(acc[r], 8);
    }
    if (s == 0) {
        #pragma unroll
        for (int r = 0; r < R; ++r) {
            int gi = b * NN + n0 + r;
            sl[gi] = satl[gi] / (acc[r] + 1e-9f);
        }
    }
}

// Pass B: ss2[m] = satr[m]*sum_n e*sl[n]; fused ratio + satr update.
__global__ __launch_bounds__(BLK) void emd_passB(
        const float* __restrict__ xyz1, const float* __restrict__ xyz2,
        const float* __restrict__ sl, float* __restrict__ satr,
        float* __restrict__ sr2, float c) {
    __shared__ float4 p[NN];                     // (x1,y1,z1,sl[n]) 64 KB
    const int b    = blockIdx.x / (MM / RPB);
    const int tile = blockIdx.x % (MM / RPB);
    const float* x1b = xyz1 + (size_t)b * NN * 3;
    const float* slb = sl + (size_t)b * NN;
    for (int n = threadIdx.x; n < NN; n += BLK)
        p[n] = make_float4(x1b[3*n], x1b[3*n+1], x1b[3*n+2], slb[n]);
    __syncthreads();

    const int g = threadIdx.x / S, s = threadIdx.x % S;
    const int m0 = tile * RPB + g * R;
    const float* qp = xyz2 + ((size_t)b * MM + m0) * 3;
    float x2[R], y2[R], z2[R], acc[R];
    #pragma unroll
    for (int r = 0; r < R; ++r) {
        x2[r] = qp[3*r]; y2[r] = qp[3*r+1]; z2[r] = qp[3*r+2]; acc[r] = 0.0f;
    }

    #pragma unroll 2
    for (int j = 0; j < NN / S; ++j) {
        float4 v = p[j * S + s];
        #pragma unroll
        for (int r = 0; r < R; ++r) {
            float dx = v.x-x2[r], dy = v.y-y2[r], dz = v.z-z2[r];
            float d2 = fmaf(dx, dx, fmaf(dy, dy, dz * dz));
            acc[r] = fmaf(EXP2F(c * d2), v.w, acc[r]);
        }
    }
    #pragma unroll
    for (int r = 0; r < R; ++r) {
        acc[r] += __shfl_xor(acc[r], 1);
        acc[r] += __shfl_xor(acc[r], 2);
        acc[r] += __shfl_xor(acc[r], 4);
        acc[r] += __shfl_xor(acc[r], 8);
    }
    if (s == 0) {
        #pragma unroll
        for (int r = 0; r < R; ++r) {
            int gi = b * MM + m0 + r;
            float sr    = satr[gi];
            float ss2   = acc[r] * sr;
            float ratio = fminf(sr / (ss2 + 1e-9f), 1.0f);
            sr2[gi]  = sr * ratio;                    // satr_old * ratio (for CA)
            satr[gi] = fmaxf(sr - ss2 * ratio, 0.0f); // next level's satr
        }
    }
}

// Fused pass C(level l) + pass A(level l+1):
//   cost += e_l*sr2[m]*sl[n]*d2 ; satl_new = max(satl - rowdec*sl, 0)
//   sl_next = satl_new / (sum_m e_{l+1}*satr_next[m] + 1e-9)
template<bool LAST>
__global__ __launch_bounds__(BLK) void emd_passCA(
        const float* __restrict__ xyz1, const float* __restrict__ xyz2,
        float* __restrict__ sl, float* __restrict__ satl,
        const float* __restrict__ sr2, const float* __restrict__ satr_next,
        float* __restrict__ out, float cl, float cn) {
    __shared__ float4 q[CHUNK];     // (x2,y2,z2,sr2[m])  32 KB
    __shared__ float  srn[CHUNK];   // satr_next[m]        8 KB
    const int b    = blockIdx.x / (NN / RPB);
    const int tile = blockIdx.x % (NN / RPB);
    const float* x2b = xyz2 + (size_t)b * MM * 3;
    const float* s2b = sr2 + (size_t)b * MM;
    const float* srb = satr_next + (size_t)b * MM;

    const int g = threadIdx.x / S, s = threadIdx.x % S;
    const int n0 = tile * RPB + g * R;
    const float* pp = xyz1 + ((size_t)b * NN + n0) * 3;
    float x1[R], y1[R], z1[R], rd[R], cost[R], acc2[R], slv[R];
    #pragma unroll
    for (int r = 0; r < R; ++r) {
        x1[r] = pp[3*r]; y1[r] = pp[3*r+1]; z1[r] = pp[3*r+2];
        rd[r] = 0.0f; cost[r] = 0.0f; acc2[r] = 0.0f;
        slv[r] = sl[b * NN + n0 + r];
    }

    for (int c0 = 0; c0 < MM; c0 += CHUNK) {
        __syncthreads();   // previous chunk fully consumed
        for (int m = threadIdx.x; m < CHUNK; m += BLK) {
            int mm = c0 + m;
            q[m] = make_float4(x2b[3*mm], x2b[3*mm+1], x2b[3*mm+2], s2b[mm]);
            if (!LAST) srn[m] = srb[mm];
        }
        __syncthreads();

        #pragma unroll 2
        for (int j = 0; j < CHUNK / S; ++j) {
            float4 v = q[j * S + s];
            float w2 = LAST ? 0.0f : srn[j * S + s];
            #pragma unroll
            for (int r = 0; r < R; ++r) {
                float dx = x1[r]-v.x, dy = y1[r]-v.y, dz = z1[r]-v.z;
                float d2 = fmaf(dx, dx, fmaf(dy, dy, dz * dz));
                float e  = EXP2F(cl * d2);
                float t  = e * v.w;             // e * satr_old*ratio
                rd[r] += t;
                cost[r] = fmaf(t, d2, cost[r]);
                if (!LAST)
                    acc2[r] = fmaf(EXP2F(cn * d2), w2, acc2[r]);
            }
        }
    }

    #pragma unroll
    for (int r = 0; r < R; ++r) {
        rd[r] += __shfl_xor(rd[r], 1);
        rd[r] += __shfl_xor(rd[r], 2);
        rd[r] += __shfl_xor(rd[r], 4);
        rd[r] += __shfl_xor(rd[r], 8);
        if (!LAST) {
            acc2[r] += __shfl_xor(acc2[r], 1);
            acc2[r] += __shfl_xor(acc2[r], 2);
            acc2[r] += __shfl_xor(acc2[r], 4);
            acc2[r] += __shfl_xor(acc2[r], 8);
        }
    }

    // cost: scale by per-row sl, sum rows, full-wave reduce, 1 atomic/wave
    float csum = 0.0f;
    #pragma unroll
    for (int r = 0; r < R; ++r) csum += cost[r] * slv[r];
    csum += __shfl_xor(csum, 1);
    csum += __shfl_xor(csum, 2);
    csum += __shfl_xor(csum, 4);
    csum += __shfl_xor(csum, 8);
    csum += __shfl_xor(csum, 16);
    csum += __shfl_xor(csum, 32);
    if ((threadIdx.x & 63) == 0)
        atomicAdd(out, csum * (1.0f / (float)(BB * NN)));

    if (s == 0) {
        #pragma unroll
        for (int r = 0; r < R; ++r) {
            int gi = b * NN + n0 + r;
            float sa = fmaxf(satl[gi] - rd[r] * slv[r], 0.0f);
            satl[gi] = sa;
            if (!LAST) sl[gi] = sa / (acc2[r] + 1e-9f);  // next level's sl
        }
    }
}

extern "C" void kernel_launch(void* const* d_in, const int* in_sizes, int n_in,
                              void* d_out, int out_size, void* d_ws, size_t ws_size,
                              hipStream_t stream) {
    const float* xyz1 = (const float*)d_in[0];   // [B,N,3]
    const float* xyz2 = (const float*)d_in[1];   // [B,M,3]
    float* out  = (float*)d_out;                 // scalar

    float* satl = (float*)d_ws;                  // B*N
    float* sl   = satl + BB * NN;                // B*N
    float* satr = sl   + BB * NN;                // B*M
    float* sr2  = satr + BB * MM;                // B*M   (total 512 KB)

    emd_init<<<(BB * NN + 255) / 256, 256, 0, stream>>>(satl, satr, out);

    const double levels[10] = {-16384.0, -4096.0, -1024.0, -256.0, -64.0,
                               -16.0, -4.0, -1.0, -0.25, 0.0};
    const double LOG2E = 1.4426950408889634;
    float c[10];
    for (int l = 0; l < 10; ++l) c[l] = (float)(levels[l] * LOG2E);

    const int gridA = BB * (NN / RPB);   // 512
    const int gridB = BB * (MM / RPB);   // 512

    emd_passA<<<gridA, BLK, 0, stream>>>(xyz1, xyz2, satl, satr, sl, c[0]);
    for (int l = 0; l < 10; ++l) {
        emd_passB<<<gridB, BLK, 0, stream>>>(xyz1, xyz2, sl, satr, sr2, c[l]);
        if (l < 9)
            emd_passCA<false><<<gridA, BLK, 0, stream>>>(
                xyz1, xyz2, sl, satl, sr2, satr, out, c[l], c[l + 1]);
        else
            emd_passCA<true><<<gridA, BLK, 0, stream>>>(
                xyz1, xyz2, sl, satl, sr2, satr, out, c[l], 0.0f);
    }
}